// Round 16
// baseline (89.443 us; speedup 1.0000x reference)
//
#include <hip/hip_runtime.h>

#define DIM 64
#define NPB 64            // nodes per bucket (primary path)
#define NPB_LOG 6
#define MAXNB 1024        // max buckets supported by LDS tables
#define ECAP 2048         // per-bucket edge capacity in LDS (mean 1024 here)

typedef unsigned short ushort_t;
typedef float f32x4 __attribute__((ext_vector_type(4)));

// ============================================================================
// out[n] = ((sum_{e:dst=n} feat[src[e]]) @ W - deg[n]*(h_e@W)) / max(deg,1)
//
// Primary path (n_nodes <= 65536), 4 dispatches:
//   K0 memset     : zero ccnt[1024]+ccur[1024]
//   K1 cc_prep2   : feat f32 -> bf16 table AND dst bucket histogram (fused)
//   K2 cc_scatter2: in-block exclusive scan of ccnt (recomputed per block),
//                   block 0 publishes coff; reserve via coff+atomicAdd(ccur),
//                   write packed (dst<<16|src) into bucket regions
//   K3 cc_fused   : R14-PROVEN kernel, verbatim: per 64-node bucket —
//                   packed->LDS stage + hist, scan, place int src list,
//                   2-deep register gather, LDS At tile, block-tiled GEMM @W
//                   + (-deg*heW)/max(deg,1) -> out.
// R15 lesson: the fused2 diet (ushort esl, packed re-read, 4-deep) REGRESSED
// the dominant kernel; pipeline compression (this round's K1/K2) is kept,
// dominant kernel restored to the proven version.
// ws: ccnt[1024]|ccur[1024]|coff[1028]|packed[epad]|featb = 9.61 MB (proven).
// ============================================================================

__device__ __forceinline__ ushort_t f2bf_rne(float f) {
    const unsigned u = __float_as_uint(f);
    return (ushort_t)((u + 0x7FFFu + ((u >> 16) & 1u)) >> 16);
}

// --- K1: feat -> bf16 table + dst bucket histogram (LDS-privatized) ---------
__global__ void __launch_bounds__(256)
cc_prep2(const float* __restrict__ feat, ushort_t* __restrict__ featb, int n_elems,
         const int* __restrict__ dst, int n_edges, int* __restrict__ ccnt, int nb) {
    __shared__ int lc[MAXNB];
    for (int i = threadIdx.x; i < nb; i += 256) lc[i] = 0;
    __syncthreads();

    const int gid    = blockIdx.x * blockDim.x + threadIdx.x;
    const int stride = gridDim.x * blockDim.x;

    for (int i = gid * 4; i + 3 < n_elems; i += stride * 4) {
        const float4 v = *(const float4*)&feat[i];
        ushort4 o;
        o.x = f2bf_rne(v.x); o.y = f2bf_rne(v.y);
        o.z = f2bf_rne(v.z); o.w = f2bf_rne(v.w);
        *(ushort4*)&featb[i] = o;
    }
    for (int i = gid; i < n_edges; i += stride)
        atomicAdd(&lc[dst[i] >> NPB_LOG], 1);
    __syncthreads();
    for (int i = threadIdx.x; i < nb; i += 256)
        if (lc[i]) atomicAdd(&ccnt[i], lc[i]);
}

// --- K2: partition packed edges; scan recomputed in-block -------------------
__global__ void __launch_bounds__(256)
cc_scatter2(const int* __restrict__ src, const int* __restrict__ dst,
            const int* __restrict__ ccnt, int* __restrict__ ccur,
            int* __restrict__ coff_g, int* __restrict__ packed,
            int n_edges, int nb) {
    __shared__ int lc[MAXNB];
    __shared__ int lbase[MAXNB];
    __shared__ int coffs[MAXNB + 4];
    __shared__ int wsum[4];
    const int tid = threadIdx.x, lane = tid & 63, wid = tid >> 6;

    // block-local exclusive scan of ccnt[0..nb) (4 elems/thread, <=1024)
    const int i0 = tid * 4;
    const int v0 = (i0     < nb) ? ccnt[i0]     : 0;
    const int v1 = (i0 + 1 < nb) ? ccnt[i0 + 1] : 0;
    const int v2 = (i0 + 2 < nb) ? ccnt[i0 + 2] : 0;
    const int v3 = (i0 + 3 < nb) ? ccnt[i0 + 3] : 0;
    const int tt = v0 + v1 + v2 + v3;
    int incl = tt;
    for (int off = 1; off < 64; off <<= 1) {
        const int u = __shfl_up(incl, off, 64);
        if (lane >= off) incl += u;
    }
    if (lane == 63) wsum[wid] = incl;
    __syncthreads();
    int wbase = 0;
    for (int w = 0; w < wid; ++w) wbase += wsum[w];
    const int ex = wbase + incl - tt;
    if (i0     < nb) coffs[i0]     = ex;
    if (i0 + 1 < nb) coffs[i0 + 1] = ex + v0;
    if (i0 + 2 < nb) coffs[i0 + 2] = ex + v0 + v1;
    if (i0 + 3 < nb) coffs[i0 + 3] = ex + v0 + v1 + v2;
    if (tid == 255) coffs[nb] = wbase + incl;
    for (int i = tid; i < nb; i += 256) lc[i] = 0;
    __syncthreads();

    if (blockIdx.x == 0)                      // publish for cc_fused
        for (int i = tid; i <= nb; i += 256) coff_g[i] = coffs[i];

    const int ch = (n_edges + gridDim.x - 1) / gridDim.x;
    const int lo = blockIdx.x * ch;
    const int hi = min(lo + ch, n_edges);
    for (int i = lo + tid; i < hi; i += 256)
        atomicAdd(&lc[dst[i] >> NPB_LOG], 1);
    __syncthreads();
    for (int i = tid; i < nb; i += 256) {
        const int c = lc[i];
        lbase[i] = c ? (coffs[i] + atomicAdd(&ccur[i], c)) : 0;
        lc[i] = 0;
    }
    __syncthreads();
    for (int i = lo + tid; i < hi; i += 256) {
        const int d = dst[i];
        const int b = d >> NPB_LOG;
        const int p = lbase[b] + atomicAdd(&lc[b], 1);
        packed[p] = (int)(((unsigned)d << 16) | (unsigned)src[i]);
    }
}

// --- shared helper: unpack 8 bf16 -> accumulate ------------------------------
#define ADD8(a, q)                                          \
    {                                                       \
        a[0] += __uint_as_float((q).x << 16);               \
        a[1] += __uint_as_float((q).x & 0xFFFF0000u);       \
        a[2] += __uint_as_float((q).y << 16);               \
        a[3] += __uint_as_float((q).y & 0xFFFF0000u);       \
        a[4] += __uint_as_float((q).z << 16);               \
        a[5] += __uint_as_float((q).z & 0xFFFF0000u);       \
        a[6] += __uint_as_float((q).w << 16);               \
        a[7] += __uint_as_float((q).w & 0xFFFF0000u);       \
    }

// --- K3: fused build + gather + transform (R14-PROVEN, verbatim) ------------
__global__ void __launch_bounds__(256)
cc_fused(const ushort_t* __restrict__ featb, const float* __restrict__ Wg,
         const float* __restrict__ h_e, const int* __restrict__ coff,
         const int* __restrict__ packed, float* __restrict__ out, int n_nodes) {
    __shared__ float Wl[DIM * DIM];       // 16 KB
    __shared__ float At[NPB][DIM + 4];    // 17 KB (stride 68)
    __shared__ int   esl_in[ECAP];        // 8 KB
    __shared__ int   esl[ECAP];           // 8 KB (dst-sorted src)
    __shared__ int   deg[NPB];
    __shared__ int   loff[NPB];
    __shared__ int   cur[NPB];
    __shared__ float heWl[DIM];

    const int t   = threadIdx.x;
    const int b   = blockIdx.x;
    const int e0  = coff[b];
    const int cnt = coff[b + 1] - e0;
    const bool fits = (cnt <= ECAP);

    for (int i = t * 4; i < DIM * DIM; i += 1024)
        *(float4*)&Wl[i] = *(const float4*)&Wg[i];
    if (t < NPB) deg[t] = 0;
    __syncthreads();

    // A: stage + histogram
    for (int i = t; i < cnt; i += 256) {
        const int pk = packed[e0 + i];
        if (fits) esl_in[i] = pk;
        atomicAdd(&deg[(((unsigned)pk) >> 16) & (NPB - 1)], 1);
    }
    __syncthreads();

    // B: scan (wave 0) and heW (wave 1)
    if (t < 64) {
        const int v = deg[t];
        int incl = v;
        for (int off = 1; off < 64; off <<= 1) {
            const int u = __shfl_up(incl, off, 64);
            if (t >= off) incl += u;
        }
        loff[t] = incl - v;
        cur[t]  = 0;
    } else if (t < 128) {
        const int c = t - 64;
        float s = 0.f;
        for (int k = 0; k < DIM; ++k) s += h_e[k] * Wl[k * DIM + c];
        heWl[c] = s;
    }
    __syncthreads();

    // C: place sorted src list
    if (fits) {
        for (int i = t; i < cnt; i += 256) {
            const int pk = esl_in[i];
            const int l  = (((unsigned)pk) >> 16) & (NPB - 1);
            esl[loff[l] + atomicAdd(&cur[l], 1)] = pk & 0xFFFF;
        }
    }
    __syncthreads();

    // D: gather
    const int grp = t >> 3;          // 0..31
    const int dq  = t & 7;           // dims 8dq..8dq+7
#pragma unroll
    for (int half = 0; half < 2; ++half) {
        const int l  = grp + half * 32;
        const int d0 = loff[l];
        const int dn = deg[l];
        float a[8] = {0.f, 0.f, 0.f, 0.f, 0.f, 0.f, 0.f, 0.f};
        if (fits) {
            int e = 0;
            for (; e + 2 <= dn; e += 2) {           // 2 independent loads
                const int s0 = esl[d0 + e];
                const int s1 = esl[d0 + e + 1];
                const uint4 q0 = *(const uint4*)&featb[(size_t)s0 * DIM + dq * 8];
                const uint4 q1 = *(const uint4*)&featb[(size_t)s1 * DIM + dq * 8];
                ADD8(a, q0);
                ADD8(a, q1);
            }
            if (e < dn) {
                const int s = esl[d0 + e];
                const uint4 q = *(const uint4*)&featb[(size_t)s * DIM + dq * 8];
                ADD8(a, q);
            }
        } else {
            // overflow slow path (statistically never; correct always)
            for (int i = 0; i < cnt; ++i) {
                const int pk = packed[e0 + i];
                if ((int)((((unsigned)pk) >> 16) & (NPB - 1)) == l) {
                    const uint4 q =
                        *(const uint4*)&featb[(size_t)(pk & 0xFFFF) * DIM + dq * 8];
                    ADD8(a, q);
                }
            }
        }
        const f32x4 v0 = {a[0], a[1], a[2], a[3]};
        const f32x4 v1 = {a[4], a[5], a[6], a[7]};
        *(f32x4*)&At[l][dq * 8]     = v0;
        *(f32x4*)&At[l][dq * 8 + 4] = v1;
    }
    __syncthreads();

    // E: GEMM + epilogue
    const int tx = t & 15, ty = t >> 4;
    float acc[4][4] = {{0.f}};
#pragma unroll 8
    for (int k = 0; k < DIM; ++k) {
        const float4 bv = *(const float4*)&Wl[k * DIM + tx * 4];
        const float a0 = At[ty * 4 + 0][k];
        const float a1 = At[ty * 4 + 1][k];
        const float a2 = At[ty * 4 + 2][k];
        const float a3 = At[ty * 4 + 3][k];
        acc[0][0] += a0 * bv.x; acc[0][1] += a0 * bv.y; acc[0][2] += a0 * bv.z; acc[0][3] += a0 * bv.w;
        acc[1][0] += a1 * bv.x; acc[1][1] += a1 * bv.y; acc[1][2] += a1 * bv.z; acc[1][3] += a1 * bv.w;
        acc[2][0] += a2 * bv.x; acc[2][1] += a2 * bv.y; acc[2][2] += a2 * bv.z; acc[2][3] += a2 * bv.w;
        acc[3][0] += a3 * bv.x; acc[3][1] += a3 * bv.y; acc[3][2] += a3 * bv.z; acc[3][3] += a3 * bv.w;
    }
    const float hw0 = heWl[tx * 4 + 0], hw1 = heWl[tx * 4 + 1];
    const float hw2 = heWl[tx * 4 + 2], hw3 = heWl[tx * 4 + 3];
    const int n0 = b << NPB_LOG;
#pragma unroll
    for (int i = 0; i < 4; ++i) {
        const int n = n0 + ty * 4 + i;
        if (n < n_nodes) {
            const float dg = (float)deg[ty * 4 + i];
            const float rd = 1.0f / fmaxf(dg, 1.0f);
            float4 o;
            o.x = (acc[i][0] - dg * hw0) * rd;
            o.y = (acc[i][1] - dg * hw1) * rd;
            o.z = (acc[i][2] - dg * hw2) * rd;
            o.w = (acc[i][3] - dg * hw3) * rd;
            *(float4*)&out[(size_t)n * DIM + tx * 4] = o;
        }
    }
}

// ============================================================================
// Fallback path (R5-proven): hist + single-block scan + atomic bucket + f32
// gather. Used only when the primary path's preconditions fail.
// ============================================================================
__global__ void __launch_bounds__(256)
compconv_hist(const int* __restrict__ dst, int* __restrict__ deg_i, int n_edges) {
    int i = blockIdx.x * blockDim.x + threadIdx.x;
    const int stride = gridDim.x * blockDim.x;
    for (; i < n_edges; i += stride)
        atomicAdd(&deg_i[dst[i]], 1);
}

__global__ void __launch_bounds__(1024)
compconv_scan1(const int* __restrict__ deg_i, int* __restrict__ offsets,
               int* __restrict__ cursor, int n) {
    __shared__ int wsum[16];
    __shared__ int s_carry;
    const int tid = threadIdx.x, lane = tid & 63, wid = tid >> 6;
    if (tid == 0) s_carry = 0;
    __syncthreads();
    const int CHUNK = 1024 * 4;
    for (int base = 0; base < n; base += CHUNK) {
        const int idx = base + tid * 4;
        int4 v = make_int4(0, 0, 0, 0);
        if (idx + 3 < n) v = *(const int4*)&deg_i[idx];
        else {
            if (idx + 0 < n) v.x = deg_i[idx + 0];
            if (idx + 1 < n) v.y = deg_i[idx + 1];
            if (idx + 2 < n) v.z = deg_i[idx + 2];
            if (idx + 3 < n) v.w = deg_i[idx + 3];
        }
        const int t = v.x + v.y + v.z + v.w;
        int incl = t;
        for (int off = 1; off < 64; off <<= 1) {
            const int u = __shfl_up(incl, off, 64);
            if (lane >= off) incl += u;
        }
        if (lane == 63) wsum[wid] = incl;
        __syncthreads();
        if (wid == 0) {
            const int w = (lane < 16) ? wsum[lane] : 0;
            int winc = w;
            for (int off = 1; off < 16; off <<= 1) {
                const int u = __shfl_up(winc, off, 64);
                if (lane >= off) winc += u;
            }
            if (lane < 16) wsum[lane] = winc - w;
        }
        __syncthreads();
        const int ex = s_carry + wsum[wid] + (incl - t);
        if (idx + 3 < n) {
            const int4 ov = make_int4(ex, ex + v.x, ex + v.x + v.y, ex + v.x + v.y + v.z);
            *(int4*)&offsets[idx] = ov;
            *(int4*)&cursor[idx]  = ov;
        } else {
            if (idx + 0 < n) { offsets[idx+0] = ex;               cursor[idx+0] = offsets[idx+0]; }
            if (idx + 1 < n) { offsets[idx+1] = ex+v.x;           cursor[idx+1] = offsets[idx+1]; }
            if (idx + 2 < n) { offsets[idx+2] = ex+v.x+v.y;       cursor[idx+2] = offsets[idx+2]; }
            if (idx + 3 < n) { offsets[idx+3] = ex+v.x+v.y+v.z;   cursor[idx+3] = offsets[idx+3]; }
        }
        __syncthreads();
        if (tid == 1023) s_carry = ex + t;
        __syncthreads();
    }
    if (tid == 0) offsets[n] = s_carry;
}

__global__ void __launch_bounds__(256)
compconv_bucket(const int* __restrict__ src, const int* __restrict__ dst,
                int* __restrict__ cursor, int* __restrict__ edge_src, int n_edges) {
    int i = blockIdx.x * blockDim.x + threadIdx.x;
    const int stride = gridDim.x * blockDim.x;
    for (; i < n_edges; i += stride) {
        const int p = atomicAdd(&cursor[dst[i]], 1);
        edge_src[p] = src[i];
    }
}

__global__ void __launch_bounds__(256)
compconv_gather(const float* __restrict__ feat, const float* __restrict__ Wg,
                const float* __restrict__ h_e, const int* __restrict__ offsets,
                const int* __restrict__ edge_src, float* __restrict__ out,
                int n_nodes) {
    __shared__ float Wl[DIM * DIM];
    for (int i = threadIdx.x * 4; i < DIM * DIM; i += blockDim.x * 4)
        *(float4*)&Wl[i] = *(const float4*)&Wg[i];
    __syncthreads();

    const int lane = threadIdx.x & 63;
    const int g    = lane >> 4;
    const int dq   = lane & 15;

    const float he = h_e[lane];
    float heW = 0.0f;
#pragma unroll
    for (int k = 0; k < DIM; ++k)
        heW += __shfl(he, k, 64) * Wl[k * DIM + lane];

    const int wave   = (blockIdx.x * blockDim.x + threadIdx.x) >> 6;
    const int nwaves = (gridDim.x * blockDim.x) >> 6;
    for (int n = wave; n < n_nodes; n += nwaves) {
        const int e0 = offsets[n];
        const int e1 = offsets[n + 1];
        float ax = 0.0f, ay = 0.0f, az = 0.0f, aw = 0.0f;
        int e = e0;
        for (; e + 8 <= e1; e += 8) {
            const int s0 = edge_src[e + g];
            const int s1 = edge_src[e + 4 + g];
            const float4 a = *(const float4*)&feat[(size_t)s0 * DIM + dq * 4];
            const float4 b = *(const float4*)&feat[(size_t)s1 * DIM + dq * 4];
            ax += a.x + b.x; ay += a.y + b.y; az += a.z + b.z; aw += a.w + b.w;
        }
        if (e + 4 <= e1) {
            const int s = edge_src[e + g];
            const float4 a = *(const float4*)&feat[(size_t)s * DIM + dq * 4];
            ax += a.x; ay += a.y; az += a.z; aw += a.w;
            e += 4;
        }
        if (g < e1 - e) {
            const int s = edge_src[e + g];
            const float4 a = *(const float4*)&feat[(size_t)s * DIM + dq * 4];
            ax += a.x; ay += a.y; az += a.z; aw += a.w;
        }
        ax += __shfl_xor(ax, 16, 64); ay += __shfl_xor(ay, 16, 64);
        az += __shfl_xor(az, 16, 64); aw += __shfl_xor(aw, 16, 64);
        ax += __shfl_xor(ax, 32, 64); ay += __shfl_xor(ay, 32, 64);
        az += __shfl_xor(az, 32, 64); aw += __shfl_xor(aw, 32, 64);

        float s = 0.0f;
#pragma unroll
        for (int q = 0; q < 16; ++q) {
            const float a0 = __shfl(ax, q, 64);
            const float a1 = __shfl(ay, q, 64);
            const float a2 = __shfl(az, q, 64);
            const float a3 = __shfl(aw, q, 64);
            s += a0 * Wl[(4 * q + 0) * DIM + lane]
               + a1 * Wl[(4 * q + 1) * DIM + lane]
               + a2 * Wl[(4 * q + 2) * DIM + lane]
               + a3 * Wl[(4 * q + 3) * DIM + lane];
        }
        const float dg = (float)(e1 - e0);
        out[(size_t)n * DIM + lane] = (s - dg * heW) / fmaxf(dg, 1.0f);
    }
}

extern "C" void kernel_launch(void* const* d_in, const int* in_sizes, int n_in,
                              void* d_out, int out_size, void* d_ws, size_t ws_size,
                              hipStream_t stream) {
    const float* feat = (const float*)d_in[0];   // (N, 64)
    const float* h_e  = (const float*)d_in[1];   // (1, 64)
    const float* W    = (const float*)d_in[2];   // (64, 64)
    const int*   src  = (const int*)d_in[3];     // (E,)
    const int*   dst  = (const int*)d_in[4];     // (E,)

    const int n_edges = in_sizes[3];
    const int n_nodes = in_sizes[0] / DIM;

    float* out = (float*)d_out;

    const int nb   = (n_nodes + NPB - 1) >> NPB_LOG;
    const int epad = (n_edges + 3) & ~3;

    // ws: ccnt[1024] | ccur[1024] | coff[1028] | packed[epad] | featb[N*64 bf16]
    const size_t need = ((size_t)(1024 + 1024 + 1028) + epad) * sizeof(int) +
                        (size_t)n_nodes * DIM * sizeof(ushort_t);
    const bool primary_ok = (n_nodes <= 65536) && (nb <= MAXNB) && (ws_size >= need);

    if (primary_ok) {
        int* ccnt   = (int*)d_ws;
        int* ccur   = ccnt + 1024;
        int* coff   = ccur + 1024;                 // 1028 slots
        int* packed = coff + 1028;
        ushort_t* featb = (ushort_t*)(packed + epad);

        hipMemsetAsync(ccnt, 0, 2048 * sizeof(int), stream);   // ccnt + ccur
        cc_prep2   <<<1024, 256, 0, stream>>>(feat, featb, n_nodes * DIM,
                                              dst, n_edges, ccnt, nb);
        cc_scatter2<<<256,  256, 0, stream>>>(src, dst, ccnt, ccur, coff,
                                              packed, n_edges, nb);
        cc_fused   <<<nb,   256, 0, stream>>>(featb, W, h_e, coff, packed,
                                              out, n_nodes);
    } else {
        // fallback: ws = deg_i[N] | cursor[N] | offsets[N+1] | edge_src[E]
        int* deg_i    = (int*)d_ws;
        int* cursor   = deg_i + n_nodes;
        int* offsets  = cursor + n_nodes;
        int* edge_src = offsets + (n_nodes + 1);

        hipMemsetAsync(deg_i, 0, (size_t)n_nodes * sizeof(int), stream);
        compconv_hist<<<1024, 256, 0, stream>>>(dst, deg_i, n_edges);
        compconv_scan1<<<1, 1024, 0, stream>>>(deg_i, offsets, cursor, n_nodes);
        compconv_bucket<<<1024, 256, 0, stream>>>(src, dst, cursor, edge_src, n_edges);
        compconv_gather<<<2048, 256, 0, stream>>>(feat, W, h_e, offsets, edge_src,
                                                  out, n_nodes);
    }
}

// Round 17
// 77.581 us; speedup vs baseline: 1.1529x; 1.1529x over previous
//
#include <hip/hip_runtime.h>

#define DIM 64
#define NPB 64            // nodes per bucket (primary path)
#define NPB_LOG 6
#define MAXNB 1024        // max buckets supported by LDS tables
#define ECAP 2048         // per-bucket edge capacity in LDS (mean 1024 here)

typedef unsigned short ushort_t;
typedef float f32x4 __attribute__((ext_vector_type(4)));

// ============================================================================
// out[n] = ((sum_{e:dst=n} feat[src[e]]) @ W - deg[n]*(h_e@W)) / max(deg,1)
//
// R14-PROVEN configuration (77.3 us measured) — restored verbatim after the
// R15/R16 pipeline-compression experiments regressed (+6/+12 us: the fused
// prep2 hist flush costs 4x the atomics, and the combined kernels lose
// back-to-back graph overlap).
//
// Primary path (n_nodes <= 65536), 5 dispatches:
//   K1 cc_prep    : feat f32 -> bf16 table + zero ccnt (folded memset)
//   K2 cc_count   : coarse per-bucket edge counts (LDS-privatized, 256 blks)
//   K3 cc_scan    : exclusive scan of <=1024 bucket counts (one block)
//   K4 cc_scatter : partition packed (dst<<16|src) edges into bucket regions
//   K5 cc_fused   : per bucket (64 nodes): packed->LDS, hist+scan+place sorted
//                   src list in LDS, register gather (8-lane groups, 2-deep),
//                   LDS At tile, block-tiled GEMM @W + norm epilogue -> out.
// ws: ccnt[1024]|ccur[1024]|coff[1028]|packed[epad]|featb = 9.61 MB (proven).
// Gather floor evidence: row-request rate ~20-25 G/s invariant under bytes/2
// (R9), ILP x2 (R15), occupancy +33% (R15), L2 slicing (R11), LDS accum (R10).
// ============================================================================

__device__ __forceinline__ ushort_t f2bf_rne(float f) {
    const unsigned u = __float_as_uint(f);
    return (ushort_t)((u + 0x7FFFu + ((u >> 16) & 1u)) >> 16);
}

// --- K1: feat -> bf16 table, and zero the bucket-count table ----------------
__global__ void __launch_bounds__(256)
cc_prep(const float* __restrict__ feat, ushort_t* __restrict__ featb,
        int n_elems, int* __restrict__ ccnt) {
    if (blockIdx.x == 0)
        for (int i = threadIdx.x; i < MAXNB; i += 256) ccnt[i] = 0;
    int i = (blockIdx.x * blockDim.x + threadIdx.x) * 4;
    const int stride = gridDim.x * blockDim.x * 4;
    for (; i + 3 < n_elems; i += stride) {
        const float4 v = *(const float4*)&feat[i];
        ushort4 o;
        o.x = f2bf_rne(v.x); o.y = f2bf_rne(v.y);
        o.z = f2bf_rne(v.z); o.w = f2bf_rne(v.w);
        *(ushort4*)&featb[i] = o;
    }
}

// --- K2: coarse bucket histogram --------------------------------------------
__global__ void __launch_bounds__(256)
cc_count(const int* __restrict__ dst, int* __restrict__ ccnt, int n_edges, int nb) {
    __shared__ int lc[MAXNB];
    for (int i = threadIdx.x; i < nb; i += 256) lc[i] = 0;
    __syncthreads();
    int i = blockIdx.x * blockDim.x + threadIdx.x;
    const int stride = gridDim.x * blockDim.x;
    for (; i < n_edges; i += stride)
        atomicAdd(&lc[dst[i] >> NPB_LOG], 1);
    __syncthreads();
    for (int i = threadIdx.x; i < nb; i += 256)
        if (lc[i]) atomicAdd(&ccnt[i], lc[i]);
}

// --- K3: exclusive scan of <=1024 bucket counts (one 256-thread block) ------
__global__ void __launch_bounds__(256)
cc_scan(const int* __restrict__ ccnt, int* __restrict__ coff, int* __restrict__ ccur,
        int nb) {
    __shared__ int wsum[4];
    const int tid = threadIdx.x, lane = tid & 63, wid = tid >> 6;
    const int i0 = tid * 4;
    const int v0 = (i0     < nb) ? ccnt[i0]     : 0;
    const int v1 = (i0 + 1 < nb) ? ccnt[i0 + 1] : 0;
    const int v2 = (i0 + 2 < nb) ? ccnt[i0 + 2] : 0;
    const int v3 = (i0 + 3 < nb) ? ccnt[i0 + 3] : 0;
    const int tt = v0 + v1 + v2 + v3;
    int incl = tt;
    for (int off = 1; off < 64; off <<= 1) {
        const int u = __shfl_up(incl, off, 64);
        if (lane >= off) incl += u;
    }
    if (lane == 63) wsum[wid] = incl;
    __syncthreads();
    int wbase = 0;
    for (int w = 0; w < wid; ++w) wbase += wsum[w];
    const int ex = wbase + incl - tt;
    if (i0     < nb) { coff[i0]     = ex;                ccur[i0]     = ex; }
    if (i0 + 1 < nb) { coff[i0 + 1] = ex + v0;           ccur[i0 + 1] = ex + v0; }
    if (i0 + 2 < nb) { coff[i0 + 2] = ex + v0 + v1;      ccur[i0 + 2] = ex + v0 + v1; }
    if (i0 + 3 < nb) { coff[i0 + 3] = ex + v0 + v1 + v2; ccur[i0 + 3] = ex + v0 + v1 + v2; }
    if (tid == 255) coff[nb] = wbase + incl;   // grand total = n_edges
}

// --- K4: partition packed edges into coarse bucket regions ------------------
__global__ void __launch_bounds__(256)
cc_scatter(const int* __restrict__ src, const int* __restrict__ dst,
           int* __restrict__ ccur, int* __restrict__ packed,
           int n_edges, int nb) {
    __shared__ int lc[MAXNB];
    __shared__ int lbase[MAXNB];
    const int ch = (n_edges + gridDim.x - 1) / gridDim.x;
    const int lo = blockIdx.x * ch;
    const int hi = min(lo + ch, n_edges);
    for (int i = threadIdx.x; i < nb; i += 256) lc[i] = 0;
    __syncthreads();
    for (int i = lo + threadIdx.x; i < hi; i += 256)
        atomicAdd(&lc[dst[i] >> NPB_LOG], 1);
    __syncthreads();
    for (int i = threadIdx.x; i < nb; i += 256) {
        const int c = lc[i];
        lbase[i] = c ? atomicAdd(&ccur[i], c) : 0;
        lc[i] = 0;
    }
    __syncthreads();
    for (int i = lo + threadIdx.x; i < hi; i += 256) {
        const int d = dst[i];
        const int b = d >> NPB_LOG;
        const int p = lbase[b] + atomicAdd(&lc[b], 1);
        packed[p] = (int)(((unsigned)d << 16) | (unsigned)src[i]);
    }
}

// --- shared helper: unpack 8 bf16 -> accumulate ------------------------------
#define ADD8(a, q)                                          \
    {                                                       \
        a[0] += __uint_as_float((q).x << 16);               \
        a[1] += __uint_as_float((q).x & 0xFFFF0000u);       \
        a[2] += __uint_as_float((q).y << 16);               \
        a[3] += __uint_as_float((q).y & 0xFFFF0000u);       \
        a[4] += __uint_as_float((q).z << 16);               \
        a[5] += __uint_as_float((q).z & 0xFFFF0000u);       \
        a[6] += __uint_as_float((q).w << 16);               \
        a[7] += __uint_as_float((q).w & 0xFFFF0000u);       \
    }

// --- K5: fused build + gather + transform, one block per 64-node bucket -----
__global__ void __launch_bounds__(256)
cc_fused(const ushort_t* __restrict__ featb, const float* __restrict__ Wg,
         const float* __restrict__ h_e, const int* __restrict__ coff,
         const int* __restrict__ packed, float* __restrict__ out, int n_nodes) {
    __shared__ float Wl[DIM * DIM];       // 16 KB
    __shared__ float At[NPB][DIM + 4];    // 17 KB (stride 68)
    __shared__ int   esl_in[ECAP];        // 8 KB
    __shared__ int   esl[ECAP];           // 8 KB (dst-sorted src)
    __shared__ int   deg[NPB];
    __shared__ int   loff[NPB];
    __shared__ int   cur[NPB];
    __shared__ float heWl[DIM];

    const int t   = threadIdx.x;
    const int b   = blockIdx.x;
    const int e0  = coff[b];
    const int cnt = coff[b + 1] - e0;
    const bool fits = (cnt <= ECAP);

    for (int i = t * 4; i < DIM * DIM; i += 1024)
        *(float4*)&Wl[i] = *(const float4*)&Wg[i];
    if (t < NPB) deg[t] = 0;
    __syncthreads();

    // A: stage + histogram
    for (int i = t; i < cnt; i += 256) {
        const int pk = packed[e0 + i];
        if (fits) esl_in[i] = pk;
        atomicAdd(&deg[(((unsigned)pk) >> 16) & (NPB - 1)], 1);
    }
    __syncthreads();

    // B: scan (wave 0) and heW (wave 1)
    if (t < 64) {
        const int v = deg[t];
        int incl = v;
        for (int off = 1; off < 64; off <<= 1) {
            const int u = __shfl_up(incl, off, 64);
            if (t >= off) incl += u;
        }
        loff[t] = incl - v;
        cur[t]  = 0;
    } else if (t < 128) {
        const int c = t - 64;
        float s = 0.f;
        for (int k = 0; k < DIM; ++k) s += h_e[k] * Wl[k * DIM + c];
        heWl[c] = s;
    }
    __syncthreads();

    // C: place sorted src list
    if (fits) {
        for (int i = t; i < cnt; i += 256) {
            const int pk = esl_in[i];
            const int l  = (((unsigned)pk) >> 16) & (NPB - 1);
            esl[loff[l] + atomicAdd(&cur[l], 1)] = pk & 0xFFFF;
        }
    }
    __syncthreads();

    // D: gather
    const int grp = t >> 3;          // 0..31
    const int dq  = t & 7;           // dims 8dq..8dq+7
#pragma unroll
    for (int half = 0; half < 2; ++half) {
        const int l  = grp + half * 32;
        const int d0 = loff[l];
        const int dn = deg[l];
        float a[8] = {0.f, 0.f, 0.f, 0.f, 0.f, 0.f, 0.f, 0.f};
        if (fits) {
            int e = 0;
            for (; e + 2 <= dn; e += 2) {           // 2 independent loads
                const int s0 = esl[d0 + e];
                const int s1 = esl[d0 + e + 1];
                const uint4 q0 = *(const uint4*)&featb[(size_t)s0 * DIM + dq * 8];
                const uint4 q1 = *(const uint4*)&featb[(size_t)s1 * DIM + dq * 8];
                ADD8(a, q0);
                ADD8(a, q1);
            }
            if (e < dn) {
                const int s = esl[d0 + e];
                const uint4 q = *(const uint4*)&featb[(size_t)s * DIM + dq * 8];
                ADD8(a, q);
            }
        } else {
            // overflow slow path (statistically never; correct always)
            for (int i = 0; i < cnt; ++i) {
                const int pk = packed[e0 + i];
                if ((int)((((unsigned)pk) >> 16) & (NPB - 1)) == l) {
                    const uint4 q =
                        *(const uint4*)&featb[(size_t)(pk & 0xFFFF) * DIM + dq * 8];
                    ADD8(a, q);
                }
            }
        }
        const f32x4 v0 = {a[0], a[1], a[2], a[3]};
        const f32x4 v1 = {a[4], a[5], a[6], a[7]};
        *(f32x4*)&At[l][dq * 8]     = v0;
        *(f32x4*)&At[l][dq * 8 + 4] = v1;
    }
    __syncthreads();

    // E: GEMM + epilogue
    const int tx = t & 15, ty = t >> 4;
    float acc[4][4] = {{0.f}};
#pragma unroll 8
    for (int k = 0; k < DIM; ++k) {
        const float4 bv = *(const float4*)&Wl[k * DIM + tx * 4];
        const float a0 = At[ty * 4 + 0][k];
        const float a1 = At[ty * 4 + 1][k];
        const float a2 = At[ty * 4 + 2][k];
        const float a3 = At[ty * 4 + 3][k];
        acc[0][0] += a0 * bv.x; acc[0][1] += a0 * bv.y; acc[0][2] += a0 * bv.z; acc[0][3] += a0 * bv.w;
        acc[1][0] += a1 * bv.x; acc[1][1] += a1 * bv.y; acc[1][2] += a1 * bv.z; acc[1][3] += a1 * bv.w;
        acc[2][0] += a2 * bv.x; acc[2][1] += a2 * bv.y; acc[2][2] += a2 * bv.z; acc[2][3] += a2 * bv.w;
        acc[3][0] += a3 * bv.x; acc[3][1] += a3 * bv.y; acc[3][2] += a3 * bv.z; acc[3][3] += a3 * bv.w;
    }
    const float hw0 = heWl[tx * 4 + 0], hw1 = heWl[tx * 4 + 1];
    const float hw2 = heWl[tx * 4 + 2], hw3 = heWl[tx * 4 + 3];
    const int n0 = b << NPB_LOG;
#pragma unroll
    for (int i = 0; i < 4; ++i) {
        const int n = n0 + ty * 4 + i;
        if (n < n_nodes) {
            const float dg = (float)deg[ty * 4 + i];
            const float rd = 1.0f / fmaxf(dg, 1.0f);
            float4 o;
            o.x = (acc[i][0] - dg * hw0) * rd;
            o.y = (acc[i][1] - dg * hw1) * rd;
            o.z = (acc[i][2] - dg * hw2) * rd;
            o.w = (acc[i][3] - dg * hw3) * rd;
            *(float4*)&out[(size_t)n * DIM + tx * 4] = o;
        }
    }
}

// ============================================================================
// Fallback path (R5-proven): hist + single-block scan + atomic bucket + f32
// gather. Used only when the primary path's preconditions fail.
// ============================================================================
__global__ void __launch_bounds__(256)
compconv_hist(const int* __restrict__ dst, int* __restrict__ deg_i, int n_edges) {
    int i = blockIdx.x * blockDim.x + threadIdx.x;
    const int stride = gridDim.x * blockDim.x;
    for (; i < n_edges; i += stride)
        atomicAdd(&deg_i[dst[i]], 1);
}

__global__ void __launch_bounds__(1024)
compconv_scan1(const int* __restrict__ deg_i, int* __restrict__ offsets,
               int* __restrict__ cursor, int n) {
    __shared__ int wsum[16];
    __shared__ int s_carry;
    const int tid = threadIdx.x, lane = tid & 63, wid = tid >> 6;
    if (tid == 0) s_carry = 0;
    __syncthreads();
    const int CHUNK = 1024 * 4;
    for (int base = 0; base < n; base += CHUNK) {
        const int idx = base + tid * 4;
        int4 v = make_int4(0, 0, 0, 0);
        if (idx + 3 < n) v = *(const int4*)&deg_i[idx];
        else {
            if (idx + 0 < n) v.x = deg_i[idx + 0];
            if (idx + 1 < n) v.y = deg_i[idx + 1];
            if (idx + 2 < n) v.z = deg_i[idx + 2];
            if (idx + 3 < n) v.w = deg_i[idx + 3];
        }
        const int t = v.x + v.y + v.z + v.w;
        int incl = t;
        for (int off = 1; off < 64; off <<= 1) {
            const int u = __shfl_up(incl, off, 64);
            if (lane >= off) incl += u;
        }
        if (lane == 63) wsum[wid] = incl;
        __syncthreads();
        if (wid == 0) {
            const int w = (lane < 16) ? wsum[lane] : 0;
            int winc = w;
            for (int off = 1; off < 16; off <<= 1) {
                const int u = __shfl_up(winc, off, 64);
                if (lane >= off) winc += u;
            }
            if (lane < 16) wsum[lane] = winc - w;
        }
        __syncthreads();
        const int ex = s_carry + wsum[wid] + (incl - t);
        if (idx + 3 < n) {
            const int4 ov = make_int4(ex, ex + v.x, ex + v.x + v.y, ex + v.x + v.y + v.z);
            *(int4*)&offsets[idx] = ov;
            *(int4*)&cursor[idx]  = ov;
        } else {
            if (idx + 0 < n) { offsets[idx+0] = ex;               cursor[idx+0] = offsets[idx+0]; }
            if (idx + 1 < n) { offsets[idx+1] = ex+v.x;           cursor[idx+1] = offsets[idx+1]; }
            if (idx + 2 < n) { offsets[idx+2] = ex+v.x+v.y;       cursor[idx+2] = offsets[idx+2]; }
            if (idx + 3 < n) { offsets[idx+3] = ex+v.x+v.y+v.z;   cursor[idx+3] = offsets[idx+3]; }
        }
        __syncthreads();
        if (tid == 1023) s_carry = ex + t;
        __syncthreads();
    }
    if (tid == 0) offsets[n] = s_carry;
}

__global__ void __launch_bounds__(256)
compconv_bucket(const int* __restrict__ src, const int* __restrict__ dst,
                int* __restrict__ cursor, int* __restrict__ edge_src, int n_edges) {
    int i = blockIdx.x * blockDim.x + threadIdx.x;
    const int stride = gridDim.x * blockDim.x;
    for (; i < n_edges; i += stride) {
        const int p = atomicAdd(&cursor[dst[i]], 1);
        edge_src[p] = src[i];
    }
}

__global__ void __launch_bounds__(256)
compconv_gather(const float* __restrict__ feat, const float* __restrict__ Wg,
                const float* __restrict__ h_e, const int* __restrict__ offsets,
                const int* __restrict__ edge_src, float* __restrict__ out,
                int n_nodes) {
    __shared__ float Wl[DIM * DIM];
    for (int i = threadIdx.x * 4; i < DIM * DIM; i += blockDim.x * 4)
        *(float4*)&Wl[i] = *(const float4*)&Wg[i];
    __syncthreads();

    const int lane = threadIdx.x & 63;
    const int g    = lane >> 4;
    const int dq   = lane & 15;

    const float he = h_e[lane];
    float heW = 0.0f;
#pragma unroll
    for (int k = 0; k < DIM; ++k)
        heW += __shfl(he, k, 64) * Wl[k * DIM + lane];

    const int wave   = (blockIdx.x * blockDim.x + threadIdx.x) >> 6;
    const int nwaves = (gridDim.x * blockDim.x) >> 6;
    for (int n = wave; n < n_nodes; n += nwaves) {
        const int e0 = offsets[n];
        const int e1 = offsets[n + 1];
        float ax = 0.0f, ay = 0.0f, az = 0.0f, aw = 0.0f;
        int e = e0;
        for (; e + 8 <= e1; e += 8) {
            const int s0 = edge_src[e + g];
            const int s1 = edge_src[e + 4 + g];
            const float4 a = *(const float4*)&feat[(size_t)s0 * DIM + dq * 4];
            const float4 b = *(const float4*)&feat[(size_t)s1 * DIM + dq * 4];
            ax += a.x + b.x; ay += a.y + b.y; az += a.z + b.z; aw += a.w + b.w;
        }
        if (e + 4 <= e1) {
            const int s = edge_src[e + g];
            const float4 a = *(const float4*)&feat[(size_t)s * DIM + dq * 4];
            ax += a.x; ay += a.y; az += a.z; aw += a.w;
            e += 4;
        }
        if (g < e1 - e) {
            const int s = edge_src[e + g];
            const float4 a = *(const float4*)&feat[(size_t)s * DIM + dq * 4];
            ax += a.x; ay += a.y; az += a.z; aw += a.w;
        }
        ax += __shfl_xor(ax, 16, 64); ay += __shfl_xor(ay, 16, 64);
        az += __shfl_xor(az, 16, 64); aw += __shfl_xor(aw, 16, 64);
        ax += __shfl_xor(ax, 32, 64); ay += __shfl_xor(ay, 32, 64);
        az += __shfl_xor(az, 32, 64); aw += __shfl_xor(aw, 32, 64);

        float s = 0.0f;
#pragma unroll
        for (int q = 0; q < 16; ++q) {
            const float a0 = __shfl(ax, q, 64);
            const float a1 = __shfl(ay, q, 64);
            const float a2 = __shfl(az, q, 64);
            const float a3 = __shfl(aw, q, 64);
            s += a0 * Wl[(4 * q + 0) * DIM + lane]
               + a1 * Wl[(4 * q + 1) * DIM + lane]
               + a2 * Wl[(4 * q + 2) * DIM + lane]
               + a3 * Wl[(4 * q + 3) * DIM + lane];
        }
        const float dg = (float)(e1 - e0);
        out[(size_t)n * DIM + lane] = (s - dg * heW) / fmaxf(dg, 1.0f);
    }
}

extern "C" void kernel_launch(void* const* d_in, const int* in_sizes, int n_in,
                              void* d_out, int out_size, void* d_ws, size_t ws_size,
                              hipStream_t stream) {
    const float* feat = (const float*)d_in[0];   // (N, 64)
    const float* h_e  = (const float*)d_in[1];   // (1, 64)
    const float* W    = (const float*)d_in[2];   // (64, 64)
    const int*   src  = (const int*)d_in[3];     // (E,)
    const int*   dst  = (const int*)d_in[4];     // (E,)

    const int n_edges = in_sizes[3];
    const int n_nodes = in_sizes[0] / DIM;

    float* out = (float*)d_out;

    const int nb   = (n_nodes + NPB - 1) >> NPB_LOG;
    const int epad = (n_edges + 3) & ~3;

    // ws: ccnt[1024] | ccur[1024] | coff[1028] | packed[epad] | featb[N*64 bf16]
    // (head = 3076 ints = 12304 B, 16-divisible; epad*4 16-divisible -> featb
    //  base is 16B-aligned for ushort4/uint4 access)
    const size_t need = ((size_t)(1024 + 1024 + 1028) + epad) * sizeof(int) +
                        (size_t)n_nodes * DIM * sizeof(ushort_t);
    const bool primary_ok = (n_nodes <= 65536) && (nb <= MAXNB) && (ws_size >= need);

    if (primary_ok) {
        int* ccnt   = (int*)d_ws;
        int* ccur   = ccnt + 1024;
        int* coff   = ccur + 1024;                 // 1028 slots
        int* packed = coff + 1028;
        ushort_t* featb = (ushort_t*)(packed + epad);

        cc_prep   <<<1024, 256, 0, stream>>>(feat, featb, n_nodes * DIM, ccnt);
        cc_count  <<<256,  256, 0, stream>>>(dst, ccnt, n_edges, nb);
        cc_scan   <<<1,    256, 0, stream>>>(ccnt, coff, ccur, nb);
        cc_scatter<<<256,  256, 0, stream>>>(src, dst, ccur, packed, n_edges, nb);
        cc_fused  <<<nb,   256, 0, stream>>>(featb, W, h_e, coff, packed, out, n_nodes);
    } else {
        // fallback: ws = deg_i[N] | cursor[N] | offsets[N+1] | edge_src[E]
        int* deg_i    = (int*)d_ws;
        int* cursor   = deg_i + n_nodes;
        int* offsets  = cursor + n_nodes;
        int* edge_src = offsets + (n_nodes + 1);

        hipMemsetAsync(deg_i, 0, (size_t)n_nodes * sizeof(int), stream);
        compconv_hist<<<1024, 256, 0, stream>>>(dst, deg_i, n_edges);
        compconv_scan1<<<1, 1024, 0, stream>>>(deg_i, offsets, cursor, n_nodes);
        compconv_bucket<<<1024, 256, 0, stream>>>(src, dst, cursor, edge_src, n_edges);
        compconv_gather<<<2048, 256, 0, stream>>>(feat, W, h_e, offsets, edge_src,
                                                  out, n_nodes);
    }
}